// Round 13
// baseline (259.401 us; speedup 1.0000x reference)
//
#include <hip/hip_runtime.h>
#include <hip/hip_bf16.h>
#include <math.h>

typedef unsigned short ushort;
typedef __attribute__((ext_vector_type(8))) unsigned short ushort8;
typedef __attribute__((ext_vector_type(8))) short s16x8;
typedef __attribute__((ext_vector_type(4))) float f32x4;

constexpr int NE = 768;      // N_EMBD
constexpr int NH = 12;       // heads
constexpr int HD = 64;       // head dim
constexpr int Bc = 4;
constexpr int Tc = 1024;
constexpr int BT = Bc * Tc;  // 4096 rows

__device__ __forceinline__ ushort f2bf(float f) {
    __hip_bfloat16 h = __float2bfloat16(f);
    return *reinterpret_cast<ushort*>(&h);
}
__device__ __forceinline__ float bf2f(ushort u) {
    return __uint_as_float(((unsigned)u) << 16);
}
__device__ __forceinline__ float softplus_f(float x) {
    return (x > 20.f) ? x : log1pf(__expf(x));
}
__device__ __forceinline__ float rcp_f(float x) {
#if __has_builtin(__builtin_amdgcn_rcpf)
    return __builtin_amdgcn_rcpf(x);
#else
    return 1.f / x;
#endif
}
__device__ __forceinline__ void gload16(const void* g, void* l) {
    __builtin_amdgcn_global_load_lds((const __attribute__((address_space(1))) void*)g,
                                     (__attribute__((address_space(3))) void*)l, 16, 0, 0);
}

// ---------------- LayerNorm: f32 in -> bf16 out (wave-shuffle reduce) ----------------
__global__ __launch_bounds__(256) void ln_kernel(const float* __restrict__ x,
                                                 const float* __restrict__ w,
                                                 const float* __restrict__ b,
                                                 ushort* __restrict__ out) {
    int row = blockIdx.x;
    const float* xr = x + (size_t)row * NE;
    int t = threadIdx.x;
    float v0 = xr[t], v1 = xr[t + 256], v2 = xr[t + 512];
    float s = v0 + v1 + v2;
    float s2 = v0 * v0 + v1 * v1 + v2 * v2;
#pragma unroll
    for (int o = 32; o > 0; o >>= 1) {
        s += __shfl_xor(s, o);
        s2 += __shfl_xor(s2, o);
    }
    __shared__ float ws[4], ws2[4];
    int wv = t >> 6;
    if ((t & 63) == 0) { ws[wv] = s; ws2[wv] = s2; }
    __syncthreads();
    float sum = ws[0] + ws[1] + ws[2] + ws[3];
    float sq = ws2[0] + ws2[1] + ws2[2] + ws2[3];
    float mean = sum * (1.0f / NE);
    float var = sq * (1.0f / NE) - mean * mean;
    float rs = rsqrtf(var + 1e-5f);
    ushort* orow = out + (size_t)row * NE;
    orow[t]       = f2bf((v0 - mean) * rs * w[t]       + b[t]);
    orow[t + 256] = f2bf((v1 - mean) * rs * w[t + 256] + b[t + 256]);
    orow[t + 512] = f2bf((v2 - mean) * rs * w[t + 512] + b[t + 512]);
}

// ---------------- fused weight convert + buffer zeroing: one launch ----------------
__device__ __forceinline__ void wconv_tile(const float* __restrict__ W,
                                           ushort* __restrict__ Wt,
                                           int K, int N, int bx, int by, int tid) {
    __shared__ float t[32][33];
    int n0 = bx * 32, k0 = by * 32;
    int c = tid & 31, r4 = tid >> 5;
#pragma unroll
    for (int i = 0; i < 4; ++i) {
        int r = r4 + i * 8;
        t[r][c] = W[(size_t)(k0 + r) * N + n0 + c];
    }
    __syncthreads();
#pragma unroll
    for (int i = 0; i < 4; ++i) {
        int r = r4 + i * 8;
        Wt[(size_t)(n0 + r) * K + k0 + c] = f2bf(t[c][r]);
    }
}

__global__ __launch_bounds__(256) void wconvert_all(
    const float* __restrict__ Wa, ushort* __restrict__ Ta,    // 768 x 2304
    const float* __restrict__ Wc, ushort* __restrict__ Tcp,   // 768 x 768
    const float* __restrict__ Wf, ushort* __restrict__ Tf,    // 768 x 3072
    const float* __restrict__ Wp, ushort* __restrict__ Tp,    // 3072 x 768
    float* __restrict__ colsum, float* __restrict__ refr_out) {
    int blk = blockIdx.x, tid = threadIdx.x;
    if (blk >= 6912) {
        int i = (blk - 6912) * 256 + tid;
        float4 z = make_float4(0.f, 0.f, 0.f, 0.f);
        if (i < 12288) ((float4*)colsum)[i] = z;
        else ((float4*)refr_out)[i - 12288] = z;
        return;
    }
    if (blk < 1728) {
        wconv_tile(Wa, Ta, 768, 2304, blk % 72, blk / 72, tid);
    } else if (blk < 2304) {
        int i = blk - 1728;
        wconv_tile(Wc, Tcp, 768, 768, i % 24, i / 24, tid);
    } else if (blk < 4608) {
        int i = blk - 2304;
        wconv_tile(Wf, Tf, 768, 3072, i % 96, i / 96, tid);
    } else {
        int i = blk - 4608;
        wconv_tile(Wp, Tp, 3072, 768, i % 24, i / 24, tid);
    }
}

// ---------------- MFMA GEMM ----------------
// 64x64 tiles use a 2-phase double-buffered pipeline (counted vmcnt, raw barriers);
// larger tiles keep the single-buffer loop.
template <int BM, int BN, int OUT_MODE, int ACT, bool RES>
__global__ __launch_bounds__(256) void mfma_gemm(
    const ushort* __restrict__ A, const ushort* __restrict__ Bt,
    const float* __restrict__ bias, const float* __restrict__ residual,
    float* __restrict__ Cf, ushort* __restrict__ Cb,
    ushort* __restrict__ Qo, ushort* __restrict__ Ko, ushort* __restrict__ Vo,
    int M, int N, int K, int NBX) {
    constexpr int NF = (BM == 128) ? 4 : 2;
    constexpr int MF = (BM == 64 && BN == 64) ? 2 : 4;
    constexpr int WN = BN / (NF * 16);
    constexpr int APASS = BM / 32, BPASS = BN / 32;
    constexpr bool DBUF = (BM == 64 && BN == 64);
    constexpr int NBUF = DBUF ? 2 : 1;
    __shared__ __align__(16) ushort As[NBUF * BM * 64];
    __shared__ __align__(16) ushort Bs[NBUF * BN * 64];
    int tid = threadIdx.x;
    int lane = tid & 63;
    int nb = gridDim.x;
    int lin = blockIdx.x;
    int nl = (lin & 7) * (nb >> 3) + (lin >> 3);
    int bx = nl % NBX, by = nl / NBX;
    int m0 = by * BM, n0 = bx * BN;
    int wave = tid >> 6;
    int wr = wave / WN, wc = wave % WN;
    f32x4 acc[MF][NF] = {};
    int srow = tid >> 3;
    int scol = (tid & 7) ^ (srow & 7);
    const ushort* ga = A + (size_t)(m0 + srow) * K + scol * 8;
    const ushort* gb = Bt + (size_t)(n0 + srow) * K + scol * 8;
    char* lA = (char*)As + tid * 16;
    char* lB = (char*)Bs + tid * 16;
    int fr = lane & 15, g = lane >> 4;
    unsigned swz = (unsigned)((fr & 7) << 4);
    const char* abase = (const char*)As + (wr * (MF * 16) + fr) * 128;
    const char* bbase = (const char*)Bs + (wc * (NF * 16) + fr) * 128;

    if constexpr (DBUF) {
        constexpr int ABYTES = BM * 64 * 2, BBYTES = BN * 64 * 2;
        int nk = K >> 6;
#pragma unroll
        for (int p = 0; p < APASS; ++p) gload16(ga + (size_t)(p * 32) * K, lA + p * 4096);
#pragma unroll
        for (int p = 0; p < BPASS; ++p) gload16(gb + (size_t)(p * 32) * K, lB + p * 4096);
        for (int k = 0; k < nk; ++k) {
            int cur = k & 1;
            if (k + 1 < nk) {
                int nxt = cur ^ 1;
                int k0 = (k + 1) << 6;
#pragma unroll
                for (int p = 0; p < APASS; ++p)
                    gload16(ga + (size_t)(p * 32) * K + k0, lA + nxt * ABYTES + p * 4096);
#pragma unroll
                for (int p = 0; p < BPASS; ++p)
                    gload16(gb + (size_t)(p * 32) * K + k0, lB + nxt * BBYTES + p * 4096);
                asm volatile("s_waitcnt vmcnt(4)" ::: "memory");
            } else {
                asm volatile("s_waitcnt vmcnt(0)" ::: "memory");
            }
            __builtin_amdgcn_s_barrier();
#pragma unroll
            for (int ks = 0; ks < 2; ++ks) {
                unsigned o = ((unsigned)(g * 16 + ks * 64)) ^ swz;
                s16x8 af[MF], bf[NF];
#pragma unroll
                for (int i = 0; i < MF; ++i)
                    af[i] = *(const s16x8*)(abase + cur * ABYTES + i * 2048 + o);
#pragma unroll
                for (int i = 0; i < NF; ++i)
                    bf[i] = *(const s16x8*)(bbase + cur * BBYTES + i * 2048 + o);
#pragma unroll
                for (int mi = 0; mi < MF; ++mi)
#pragma unroll
                    for (int ni = 0; ni < NF; ++ni)
                        acc[mi][ni] = __builtin_amdgcn_mfma_f32_16x16x32_bf16(af[mi], bf[ni], acc[mi][ni], 0, 0, 0);
            }
            asm volatile("s_waitcnt lgkmcnt(0)" ::: "memory");
            __builtin_amdgcn_s_barrier();
        }
    } else {
        for (int k0 = 0; k0 < K; k0 += 64) {
#pragma unroll
            for (int p = 0; p < APASS; ++p)
                gload16(ga + (size_t)(p * 32) * K + k0, lA + p * 4096);
#pragma unroll
            for (int p = 0; p < BPASS; ++p)
                gload16(gb + (size_t)(p * 32) * K + k0, lB + p * 4096);
            __syncthreads();
#pragma unroll
            for (int ks = 0; ks < 2; ++ks) {
                unsigned o = ((unsigned)(g * 16 + ks * 64)) ^ swz;
                s16x8 af[MF], bf[NF];
#pragma unroll
                for (int i = 0; i < MF; ++i) af[i] = *(const s16x8*)(abase + i * 2048 + o);
#pragma unroll
                for (int i = 0; i < NF; ++i) bf[i] = *(const s16x8*)(bbase + i * 2048 + o);
#pragma unroll
                for (int mi = 0; mi < MF; ++mi)
#pragma unroll
                    for (int ni = 0; ni < NF; ++ni)
                        acc[mi][ni] = __builtin_amdgcn_mfma_f32_16x16x32_bf16(af[mi], bf[ni], acc[mi][ni], 0, 0, 0);
            }
            __syncthreads();
        }
    }
#pragma unroll
    for (int mi = 0; mi < MF; ++mi) {
#pragma unroll
        for (int ni = 0; ni < NF; ++ni) {
#pragma unroll
            for (int j = 0; j < 4; ++j) {
                int row = m0 + wr * (MF * 16) + mi * 16 + g * 4 + j;
                int col = n0 + wc * (NF * 16) + ni * 16 + fr;
                float v = acc[mi][ni][j] + bias[col];
                if (ACT == 1) v = 0.5f * v * (1.0f + erff(v * 0.70710678118654752f));
                if (RES) v += residual[(size_t)row * N + col];
                if (OUT_MODE == 0) {
                    Cf[(size_t)row * N + col] = v;
                } else if (OUT_MODE == 1) {
                    Cb[(size_t)row * N + col] = f2bf(v);
                } else {
                    int which = col >= 1536 ? 2 : (col >= 768 ? 1 : 0);
                    int rem = col - which * 768;
                    int hh = rem >> 6, d = rem & 63;
                    int b_ = row >> 10, t_ = row & 1023;
                    if (which == 2)
                        Vo[((size_t)(b_ * NH + hh) * HD + d) * Tc + t_] = f2bf(v);
                    else {
                        ushort* dst = which == 0 ? Qo : Ko;
                        dst[((size_t)(b_ * NH + hh) * Tc + t_) * HD + d] = f2bf(v);
                    }
                }
            }
        }
    }
}

// ============ FAST attention: P-store scheme, 2-wave blocks, 64-key steps ============
// Block = one 16-row q-tile (t = 0..63) of one head; 128 thr = 2 waves (kh key-halves).
// Step = 64 keys (4 QK-tiles, 2 panel chunks) -> <=8 serial steps per wave.
// P = exp(s*0.125-8) bf16 in MFMA-A-fragment layout per 32-key chunk:
// lane l elem j <-> (q = l&15, k = chunk*32 + (l>>4)*8 + j); 1KB / chunk.
// panel(bh,t) = Pbuf + (bh*1056 + (t+1)^2/4)*512 ushorts; nchunk(t) = (t+2)>>1.

__global__ __launch_bounds__(128, 6) void attn_P(
    const ushort* __restrict__ Qp, const ushort* __restrict__ Kp,
    ushort* __restrict__ Pbuf, float* __restrict__ denom, float* __restrict__ colsum) {
    int beta = blockIdx.x;
    int tq = 63 - beta / 48;
    int bh = beta % 48;
    int tid = threadIdx.x;
    int kh = tid >> 6, lane = tid & 63, qlane = lane & 15, g = lane >> 4;
    __shared__ ushort plds[2][16][72];
    __shared__ float cs[1056];
    __shared__ float dden[2][16];
    int nst = (tq + 4) >> 2;        // 64-key steps
    int nchunk = (tq + 2) >> 1;     // valid 32-key chunks
    int smid = (nst + 1) >> 1;
    int slo = kh ? smid : 0, shi = kh ? nst : smid;  // <=8 per wave
    int kmaxc = (tq + 1) * 16;
    for (int i = tid; i < 1056; i += 128) cs[i] = 0.f;
    const ushort* Qb = Qp + (size_t)bh * Tc * HD;
    const ushort* Kb = Kp + (size_t)bh * Tc * HD;
    const ushort* qr = Qb + (size_t)(tq * 16 + qlane) * HD + g * 8;
    s16x8 qf0 = *(const s16x8*)qr;
    s16x8 qf1 = *(const s16x8*)(qr + 32);
    ushort* panel = Pbuf + ((size_t)bh * 1056 + (unsigned)(((tq + 1) * (tq + 1)) >> 2)) * 512;
    int q = tq * 16 + qlane;
    s16x8 preg0[8], preg1[8];
    float dpart = 0.f;
    // sweep A: QK^T (swapped) -> P; 4 key-tiles per step; panel store; denom partials
#pragma unroll
    for (int ss = 0; ss < 8; ++ss) {
        int s = slo + ss;
        if (s < shi) {
#pragma unroll
            for (int kq = 0; kq < 4; ++kq) {
                int kt = 4 * s + kq;
                if (kt <= tq) {
                    const ushort* kr = Kb + (size_t)(kt * 16 + qlane) * HD + g * 8;
                    s16x8 kf0 = *(const s16x8*)kr;
                    s16x8 kf1 = *(const s16x8*)(kr + 32);
                    f32x4 z = {0.f, 0.f, 0.f, 0.f};
                    z = __builtin_amdgcn_mfma_f32_16x16x32_bf16(kf0, qf0, z, 0, 0, 0);
                    z = __builtin_amdgcn_mfma_f32_16x16x32_bf16(kf1, qf1, z, 0, 0, 0);
#pragma unroll
                    for (int j = 0; j < 4; ++j) {
                        int key = kt * 16 + g * 4 + j;
                        float p = (key <= q) ? __expf(z[j] * 0.125f - 8.f) : 0.f;
                        dpart += p;
                        plds[kh][qlane][kq * 16 + g * 4 + j] = f2bf(p);
                    }
                } else {
#pragma unroll
                    for (int j = 0; j < 4; ++j)
                        plds[kh][qlane][kq * 16 + g * 4 + j] = 0;
                }
            }
            s16x8 p0 = *(const s16x8*)&plds[kh][qlane][g * 8];
            s16x8 p1 = *(const s16x8*)&plds[kh][qlane][32 + g * 8];
            preg0[ss] = p0;
            preg1[ss] = p1;
            *(s16x8*)(panel + (size_t)(2 * s) * 512 + lane * 8) = p0;
            if (2 * s + 1 < nchunk)
                *(s16x8*)(panel + (size_t)(2 * s + 1) * 512 + lane * 8) = p1;
        }
    }
    dpart += __shfl_xor(dpart, 16);
    dpart += __shfl_xor(dpart, 32);
    if (lane < 16) dden[kh][lane] = dpart;
    __syncthreads();
    float dsum = dden[0][qlane] + dden[1][qlane];
    if (tid < 16) denom[(size_t)bh * Tc + tq * 16 + tid] = dden[0][tid] + dden[1][tid];
    float dinvq = rcp_f(dsum);
    // sweep B: colsum from registers
#pragma unroll
    for (int ss = 0; ss < 8; ++ss) {
        int s = slo + ss;
        if (s < shi) {
#pragma unroll
            for (int c = 0; c < 2; ++c) {
                s16x8 v8 = c ? preg1[ss] : preg0[ss];
                int k0 = s * 64 + c * 32 + g * 8;
#pragma unroll
                for (int j = 0; j < 8; ++j) {
                    float r = bf2f((ushort)v8[j]) * dinvq;
                    r += __shfl_xor(r, 1);
                    r += __shfl_xor(r, 2);
                    r += __shfl_xor(r, 4);
                    r += __shfl_xor(r, 8);
                    if (qlane == 0) cs[k0 + j] += r;
                }
            }
        }
    }
    __syncthreads();
    for (int i = tid; i < kmaxc; i += 128)
        atomicAdd(&colsum[(size_t)bh * Tc + i], cs[i]);
}

// attn_CD: 64-key steps; pt carried in registers between sweep C and sweep D.
__global__ __launch_bounds__(128, 6) void attn_CD(
    const ushort* __restrict__ Pbuf, const ushort* __restrict__ Vt,
    const float* __restrict__ denom, const float* __restrict__ colsum,
    const float* __restrict__ refr_in,
    const float* __restrict__ threshold, const float* __restrict__ leak,
    const float* __restrict__ steepness, const float* __restrict__ refr_strength,
    const float* __restrict__ cross_w,
    ushort* __restrict__ ybuf, float* __restrict__ refr_out) {
    int beta = blockIdx.x;
    int tq = 63 - beta / 48;
    int bh = beta % 48;
    int b = bh / NH, h = bh - b * NH;
    int tid = threadIdx.x;
    int kh = tid >> 6, lane = tid & 63, qlane = lane & 15, g = lane >> 4;
    __shared__ float eff[1056];
    __shared__ float cs[1056];
    __shared__ float msum[2][16];
    __shared__ float minvL[16];
    __shared__ float ymrg[16][68];
    int nst = (tq + 4) >> 2;
    int nchunk = (tq + 2) >> 1;
    int smid = (nst + 1) >> 1;
    int slo = kh ? smid : 0, shi = kh ? nst : smid;  // <=8 per wave
    int kmaxc = (tq + 1) * 16;
    float thr = fabsf(threshold[h]) * 0.1f;
    float lk = 1.f / (1.f + __expf(-leak[h]));
    float lk1m = 1.f - lk;
    float stp = softplus_f(steepness[h]);
    float rfs = softplus_f(refr_strength[h]);
    float crw = 1.f / (1.f + __expf(-cross_w[h]));
    for (int i = tid; i < 1056; i += 128) {
        eff[i] = (i < kmaxc)
                     ? thr + rfs * (colsum[(size_t)bh * Tc + i] * (1.f / 1024.f))
                           + crw * refr_in[(size_t)b * Tc + i]
                     : 0.f;
        cs[i] = 0.f;
    }
    float dinvq = rcp_f(denom[(size_t)bh * Tc + tq * 16 + qlane]);
    __syncthreads();
    const ushort* panel =
        Pbuf + ((size_t)bh * 1056 + (unsigned)(((tq + 1) * (tq + 1)) >> 2)) * 512;
    // sweep C: panel read (2 chunks/step, issued together); LIF; pt in registers
    s16x8 pt0[8], pt1[8];
    float msp = 0.f;
#pragma unroll
    for (int ss = 0; ss < 8; ++ss) {
        int s = slo + ss;
        if (s < shi) {
            const ushort* pb = panel + (size_t)(2 * s) * 512 + lane * 8;
            s16x8 v0 = *(const s16x8*)pb;
            s16x8 v1 = {};
            if (2 * s + 1 < nchunk) v1 = *(const s16x8*)(pb + 512);
            int k0 = s * 64 + g * 8;
            s16x8 pw0, pw1;
#pragma unroll
            for (int j = 0; j < 8; ++j) {
                float p = bf2f((ushort)v0[j]) * dinvq;
                float fire = rcp_f(1.f + __expf(-stp * (p - eff[k0 + j])));
                float pt = p * (lk + lk1m * fire);
                msp += pt;
                pw0[j] = (short)f2bf(pt);
            }
#pragma unroll
            for (int j = 0; j < 8; ++j) {
                float p = bf2f((ushort)v1[j]) * dinvq;
                float fire = rcp_f(1.f + __expf(-stp * (p - eff[k0 + 32 + j])));
                float pt = p * (lk + lk1m * fire);
                msp += pt;
                pw1[j] = (short)f2bf(pt);
            }
            pt0[ss] = pw0;
            pt1[ss] = pw1;
        }
    }
    msp += __shfl_xor(msp, 16);
    msp += __shfl_xor(msp, 32);
    if (lane < 16) msum[kh][lane] = msp;
    __syncthreads();
    if (tid < 16) minvL[tid] = rcp_f(msum[0][tid] + msum[1][tid] + 1e-8f);
    __syncthreads();
    float minvq = minvL[qlane];
    const ushort* Vh = Vt + (size_t)bh * HD * Tc;
    f32x4 accY[4] = {};
    // sweep D: PV MFMA (8/step) + refractory colsum (cs[k] owned by one lane)
#pragma unroll
    for (int ss = 0; ss < 8; ++ss) {
        int s = slo + ss;
        if (s < shi) {
#pragma unroll
            for (int c = 0; c < 2; ++c) {
                s16x8 pa = c ? pt1[ss] : pt0[ss];
                int k0 = s * 64 + c * 32 + g * 8;
#pragma unroll
                for (int j = 0; j < 8; ++j) {
                    float r = bf2f((ushort)pa[j]) * minvq;
                    r += __shfl_xor(r, 1);
                    r += __shfl_xor(r, 2);
                    r += __shfl_xor(r, 4);
                    r += __shfl_xor(r, 8);
                    if (qlane == 0) cs[k0 + j] += r;
                }
#pragma unroll
                for (int dt = 0; dt < 4; ++dt) {
                    const ushort* vp = Vh + (size_t)(dt * 16 + qlane) * Tc + k0 - g * 8 + g * 8;
                    vp = Vh + (size_t)(dt * 16 + qlane) * Tc + s * 64 + c * 32 + g * 8;
                    s16x8 vf = *(const s16x8*)vp;
                    accY[dt] = __builtin_amdgcn_mfma_f32_16x16x32_bf16(pa, vf, accY[dt], 0, 0, 0);
                }
            }
        }
    }
    if (kh == 1) {
#pragma unroll
        for (int dt = 0; dt < 4; ++dt)
#pragma unroll
            for (int j = 0; j < 4; ++j)
                ymrg[g * 4 + j][dt * 16 + qlane] = accY[dt][j];
    }
    __syncthreads();
    if (kh == 0) {
#pragma unroll
        for (int dt = 0; dt < 4; ++dt)
#pragma unroll
            for (int j = 0; j < 4; ++j) {
                float y = (accY[dt][j] + ymrg[g * 4 + j][dt * 16 + qlane]) * minvL[g * 4 + j];
                ybuf[(size_t)(b * Tc + tq * 16 + g * 4 + j) * NE + h * 64 + dt * 16 + qlane] =
                    f2bf(y);
            }
    }
    for (int i = tid; i < kmaxc; i += 128)
        atomicAdd(&refr_out[(size_t)b * Tc + i], cs[i] * (1.f / (NH * Tc)));
}

// ---------------- launcher ----------------
extern "C" void kernel_launch(void* const* d_in, const int* in_sizes, int n_in,
                              void* d_out, int out_size, void* d_ws, size_t ws_size,
                              hipStream_t stream) {
    const float* x        = (const float*)d_in[0];
    const float* refr     = (const float*)d_in[1];
    const float* ln1_w    = (const float*)d_in[2];
    const float* ln1_b    = (const float*)d_in[3];
    const float* c_attn_w = (const float*)d_in[4];
    const float* c_attn_b = (const float*)d_in[5];
    const float* c_proj_w = (const float*)d_in[6];
    const float* c_proj_b = (const float*)d_in[7];
    const float* threshold = (const float*)d_in[8];
    const float* leak      = (const float*)d_in[9];
    const float* steepness = (const float*)d_in[10];
    const float* refractory_strength = (const float*)d_in[11];
    const float* cross_layer_weight  = (const float*)d_in[12];
    const float* ln2_w    = (const float*)d_in[13];
    const float* ln2_b    = (const float*)d_in[14];
    const float* fc_w     = (const float*)d_in[15];
    const float* fc_b     = (const float*)d_in[16];
    const float* proj_w   = (const float*)d_in[17];
    const float* proj_b   = (const float*)d_in[18];

    // workspace layout (bytes)
    char* ws = (char*)d_ws;
    ushort* hbuf   = (ushort*)(ws + 0);         // bf16 [4096][768]
    ushort* qb     = (ushort*)(ws + 6291456);   // bf16 [b,h,t,d]
    ushort* kb     = (ushort*)(ws + 12582912);  // bf16 [b,h,t,d]
    ushort* vtg    = (ushort*)(ws + 18874368);  // bf16 V^T [b,h,d,t]
    ushort* ybuf   = (ushort*)(ws + 25165824);  // bf16 [4096][768]
    ushort* fc_act = (ushort*)(ws + 6291456);   // bf16 [4096][3072], overlaps q/k/v/y (post-attn)
    float*  denomb = (float*)(ws + 31457280);   // [48][1024]
    float*  colsum = (float*)(ws + 31653888);   // [48][1024]
    ushort* wt_attn  = (ushort*)(ws + 31850496);
    ushort* wt_cproj = (ushort*)(ws + 35389440);
    ushort* wt_fc    = (ushort*)(ws + 36569088);
    ushort* wt_proj  = (ushort*)(ws + 41287680);
    ushort* Pbuf     = (ushort*)(ws + 46006272); // bf16 packed causal P, 51,904,512 B

    float* xout = (float*)d_out;
    float* refr_out = xout + (size_t)BT * NE;

    // wconvert + zero colsum/refr_out in one launch (6912 conv blocks + 52 zero blocks)
    wconvert_all<<<6964, 256, 0, stream>>>(c_attn_w, wt_attn, c_proj_w, wt_cproj,
                                           fc_w, wt_fc, proj_w, wt_proj,
                                           colsum, refr_out);

    ln_kernel<<<BT, 256, 0, stream>>>(x, ln1_w, ln1_b, hbuf);

    // qkv: M=4096 N=2304 K=768, 64x128 tiles -> 1152 blocks
    mfma_gemm<64, 128, 2, 0, false><<<1152, 256, 0, stream>>>(
        hbuf, wt_attn, c_attn_b, nullptr, nullptr, nullptr, qb, kb, vtg,
        BT, 3 * NE, NE, 18);

    attn_P<<<48 * 64, 128, 0, stream>>>(qb, kb, Pbuf, denomb, colsum);
    attn_CD<<<48 * 64, 128, 0, stream>>>(
        Pbuf, vtg, denomb, colsum, refr, threshold, leak, steepness,
        refractory_strength, cross_layer_weight, ybuf, refr_out);

    // c_proj: M=4096 N=768 K=768, 64x64 dbuf tiles -> 768 blocks
    mfma_gemm<64, 64, 0, 0, true><<<768, 256, 0, stream>>>(
        ybuf, wt_cproj, c_proj_b, x, xout, nullptr, nullptr, nullptr, nullptr,
        BT, NE, NE, 12);

    ln_kernel<<<BT, 256, 0, stream>>>(xout, ln2_w, ln2_b, hbuf);

    // fc: M=4096 N=3072 K=768, 128x128 tiles -> 768 blocks
    mfma_gemm<128, 128, 1, 1, false><<<768, 256, 0, stream>>>(
        hbuf, wt_fc, fc_b, nullptr, nullptr, fc_act, nullptr, nullptr, nullptr,
        BT, 4 * NE, NE, 24);

    // proj: M=4096 N=768 K=3072, 64x64 dbuf tiles -> 768 blocks
    mfma_gemm<64, 64, 0, 0, true><<<768, 256, 0, stream>>>(
        fc_act, wt_proj, proj_b, xout, xout, nullptr, nullptr, nullptr, nullptr,
        BT, NE, 4 * NE, 12);
}

// Round 14
// 256.040 us; speedup vs baseline: 1.0131x; 1.0131x over previous
//
#include <hip/hip_runtime.h>
#include <hip/hip_bf16.h>
#include <math.h>

typedef unsigned short ushort;
typedef __attribute__((ext_vector_type(8))) unsigned short ushort8;
typedef __attribute__((ext_vector_type(8))) short s16x8;
typedef __attribute__((ext_vector_type(4))) float f32x4;

constexpr int NE = 768;      // N_EMBD
constexpr int NH = 12;       // heads
constexpr int HD = 64;       // head dim
constexpr int Bc = 4;
constexpr int Tc = 1024;
constexpr int BT = Bc * Tc;  // 4096 rows

__device__ __forceinline__ ushort f2bf(float f) {
    __hip_bfloat16 h = __float2bfloat16(f);
    return *reinterpret_cast<ushort*>(&h);
}
__device__ __forceinline__ float bf2f(ushort u) {
    return __uint_as_float(((unsigned)u) << 16);
}
__device__ __forceinline__ float softplus_f(float x) {
    return (x > 20.f) ? x : log1pf(__expf(x));
}
__device__ __forceinline__ float rcp_f(float x) {
#if __has_builtin(__builtin_amdgcn_rcpf)
    return __builtin_amdgcn_rcpf(x);
#else
    return 1.f / x;
#endif
}
__device__ __forceinline__ void gload16(const void* g, void* l) {
    __builtin_amdgcn_global_load_lds((const __attribute__((address_space(1))) void*)g,
                                     (__attribute__((address_space(3))) void*)l, 16, 0, 0);
}

// ---------------- LayerNorm: f32 in -> bf16 out (wave-shuffle reduce) ----------------
__device__ __forceinline__ void ln_row(const float* __restrict__ x,
                                       const float* __restrict__ w,
                                       const float* __restrict__ b,
                                       ushort* __restrict__ out, int row, int t) {
    const float* xr = x + (size_t)row * NE;
    float v0 = xr[t], v1 = xr[t + 256], v2 = xr[t + 512];
    float s = v0 + v1 + v2;
    float s2 = v0 * v0 + v1 * v1 + v2 * v2;
#pragma unroll
    for (int o = 32; o > 0; o >>= 1) {
        s += __shfl_xor(s, o);
        s2 += __shfl_xor(s2, o);
    }
    __shared__ float lws[4], lws2[4];
    int wv = t >> 6;
    if ((t & 63) == 0) { lws[wv] = s; lws2[wv] = s2; }
    __syncthreads();
    float sum = lws[0] + lws[1] + lws[2] + lws[3];
    float sq = lws2[0] + lws2[1] + lws2[2] + lws2[3];
    float mean = sum * (1.0f / NE);
    float var = sq * (1.0f / NE) - mean * mean;
    float rs = rsqrtf(var + 1e-5f);
    ushort* orow = out + (size_t)row * NE;
    orow[t]       = f2bf((v0 - mean) * rs * w[t]       + b[t]);
    orow[t + 256] = f2bf((v1 - mean) * rs * w[t + 256] + b[t + 256]);
    orow[t + 512] = f2bf((v2 - mean) * rs * w[t + 512] + b[t + 512]);
}

__global__ __launch_bounds__(256) void ln_kernel(const float* __restrict__ x,
                                                 const float* __restrict__ w,
                                                 const float* __restrict__ b,
                                                 ushort* __restrict__ out) {
    ln_row(x, w, b, out, blockIdx.x, threadIdx.x);
}

// ---------------- fused weight convert + zeroing + LN1: one launch ----------------
__device__ __forceinline__ void wconv_tile(const float* __restrict__ W,
                                           ushort* __restrict__ Wt,
                                           int K, int N, int bx, int by, int tid) {
    __shared__ float t[32][33];
    int n0 = bx * 32, k0 = by * 32;
    int c = tid & 31, r4 = tid >> 5;
#pragma unroll
    for (int i = 0; i < 4; ++i) {
        int r = r4 + i * 8;
        t[r][c] = W[(size_t)(k0 + r) * N + n0 + c];
    }
    __syncthreads();
#pragma unroll
    for (int i = 0; i < 4; ++i) {
        int r = r4 + i * 8;
        Wt[(size_t)(n0 + r) * K + k0 + c] = f2bf(t[c][r]);
    }
}

__global__ __launch_bounds__(256) void wconvert_all(
    const float* __restrict__ Wa, ushort* __restrict__ Ta,    // 768 x 2304
    const float* __restrict__ Wc, ushort* __restrict__ Tcp,   // 768 x 768
    const float* __restrict__ Wf, ushort* __restrict__ Tf,    // 768 x 3072
    const float* __restrict__ Wp, ushort* __restrict__ Tp,    // 3072 x 768
    float* __restrict__ colsum, float* __restrict__ refr_out,
    const float* __restrict__ x, const float* __restrict__ ln1_w,
    const float* __restrict__ ln1_b, ushort* __restrict__ hbuf) {
    int blk = blockIdx.x, tid = threadIdx.x;
    if (blk >= 6964) {
        // LN1: rows 0..4095
        ln_row(x, ln1_w, ln1_b, hbuf, blk - 6964, tid);
        return;
    }
    if (blk >= 6912) {
        int i = (blk - 6912) * 256 + tid;
        float4 z = make_float4(0.f, 0.f, 0.f, 0.f);
        if (i < 12288) ((float4*)colsum)[i] = z;
        else ((float4*)refr_out)[i - 12288] = z;
        return;
    }
    if (blk < 1728) {
        wconv_tile(Wa, Ta, 768, 2304, blk % 72, blk / 72, tid);
    } else if (blk < 2304) {
        int i = blk - 1728;
        wconv_tile(Wc, Tcp, 768, 768, i % 24, i / 24, tid);
    } else if (blk < 4608) {
        int i = blk - 2304;
        wconv_tile(Wf, Tf, 768, 3072, i % 96, i / 96, tid);
    } else {
        int i = blk - 4608;
        wconv_tile(Wp, Tp, 3072, 768, i % 24, i / 24, tid);
    }
}

// ---------------- MFMA GEMM ----------------
// 64x64 tiles use a 2-phase double-buffered pipeline (counted vmcnt, raw barriers);
// larger tiles keep the single-buffer loop.
// OUT_MODE: 0=f32 store, 1=bf16 store, 2=qkv scatter (V^T), 3=f32 atomicAdd (split-K;
//   bias added by split 0 only; target must already hold the residual).
// K = per-split K-length; KLD = leading dim of A/Bt; NSPLIT = K-splits (grid multiple).
template <int BM, int BN, int OUT_MODE, int ACT, bool RES>
__global__ __launch_bounds__(256) void mfma_gemm(
    const ushort* __restrict__ A, const ushort* __restrict__ Bt,
    const float* __restrict__ bias, const float* __restrict__ residual,
    float* __restrict__ Cf, ushort* __restrict__ Cb,
    ushort* __restrict__ Qo, ushort* __restrict__ Ko, ushort* __restrict__ Vo,
    int M, int N, int K, int NBX, int KLD, int NSPLIT) {
    constexpr int NF = (BM == 128) ? 4 : 2;
    constexpr int MF = (BM == 64 && BN == 64) ? 2 : 4;
    constexpr int WN = BN / (NF * 16);
    constexpr int APASS = BM / 32, BPASS = BN / 32;
    constexpr bool DBUF = (BM == 64 && BN == 64);
    constexpr int NBUF = DBUF ? 2 : 1;
    __shared__ __align__(16) ushort As[NBUF * BM * 64];
    __shared__ __align__(16) ushort Bs[NBUF * BN * 64];
    int tid = threadIdx.x;
    int lane = tid & 63;
    int nb = gridDim.x;
    int lin = blockIdx.x;
    int nl = (lin & 7) * (nb >> 3) + (lin >> 3);
    int nper = nb / NSPLIT;
    int sp = nl / nper;
    int rem2 = nl - sp * nper;
    int bx = rem2 % NBX, by = rem2 / NBX;
    int m0 = by * BM, n0 = bx * BN;
    int kbase = sp * K;
    int wave = tid >> 6;
    int wr = wave / WN, wc = wave % WN;
    f32x4 acc[MF][NF] = {};
    int srow = tid >> 3;
    int scol = (tid & 7) ^ (srow & 7);
    const ushort* ga = A + (size_t)(m0 + srow) * KLD + kbase + scol * 8;
    const ushort* gb = Bt + (size_t)(n0 + srow) * KLD + kbase + scol * 8;
    char* lA = (char*)As + tid * 16;
    char* lB = (char*)Bs + tid * 16;
    int fr = lane & 15, g = lane >> 4;
    unsigned swz = (unsigned)((fr & 7) << 4);
    const char* abase = (const char*)As + (wr * (MF * 16) + fr) * 128;
    const char* bbase = (const char*)Bs + (wc * (NF * 16) + fr) * 128;

    if constexpr (DBUF) {
        constexpr int ABYTES = BM * 64 * 2, BBYTES = BN * 64 * 2;
        int nk = K >> 6;
#pragma unroll
        for (int p = 0; p < APASS; ++p) gload16(ga + (size_t)(p * 32) * KLD, lA + p * 4096);
#pragma unroll
        for (int p = 0; p < BPASS; ++p) gload16(gb + (size_t)(p * 32) * KLD, lB + p * 4096);
        for (int k = 0; k < nk; ++k) {
            int cur = k & 1;
            if (k + 1 < nk) {
                int nxt = cur ^ 1;
                int k0 = (k + 1) << 6;
#pragma unroll
                for (int p = 0; p < APASS; ++p)
                    gload16(ga + (size_t)(p * 32) * KLD + k0, lA + nxt * ABYTES + p * 4096);
#pragma unroll
                for (int p = 0; p < BPASS; ++p)
                    gload16(gb + (size_t)(p * 32) * KLD + k0, lB + nxt * BBYTES + p * 4096);
                asm volatile("s_waitcnt vmcnt(4)" ::: "memory");
            } else {
                asm volatile("s_waitcnt vmcnt(0)" ::: "memory");
            }
            __builtin_amdgcn_s_barrier();
#pragma unroll
            for (int ks = 0; ks < 2; ++ks) {
                unsigned o = ((unsigned)(g * 16 + ks * 64)) ^ swz;
                s16x8 af[MF], bf[NF];
#pragma unroll
                for (int i = 0; i < MF; ++i)
                    af[i] = *(const s16x8*)(abase + cur * ABYTES + i * 2048 + o);
#pragma unroll
                for (int i = 0; i < NF; ++i)
                    bf[i] = *(const s16x8*)(bbase + cur * BBYTES + i * 2048 + o);
#pragma unroll
                for (int mi = 0; mi < MF; ++mi)
#pragma unroll
                    for (int ni = 0; ni < NF; ++ni)
                        acc[mi][ni] = __builtin_amdgcn_mfma_f32_16x16x32_bf16(af[mi], bf[ni], acc[mi][ni], 0, 0, 0);
            }
            asm volatile("s_waitcnt lgkmcnt(0)" ::: "memory");
            __builtin_amdgcn_s_barrier();
        }
    } else {
        for (int k0 = 0; k0 < K; k0 += 64) {
#pragma unroll
            for (int p = 0; p < APASS; ++p)
                gload16(ga + (size_t)(p * 32) * KLD + k0, lA + p * 4096);
#pragma unroll
            for (int p = 0; p < BPASS; ++p)
                gload16(gb + (size_t)(p * 32) * KLD + k0, lB + p * 4096);
            __syncthreads();
#pragma unroll
            for (int ks = 0; ks < 2; ++ks) {
                unsigned o = ((unsigned)(g * 16 + ks * 64)) ^ swz;
                s16x8 af[MF], bf[NF];
#pragma unroll
                for (int i = 0; i < MF; ++i) af[i] = *(const s16x8*)(abase + i * 2048 + o);
#pragma unroll
                for (int i = 0; i < NF; ++i) bf[i] = *(const s16x8*)(bbase + i * 2048 + o);
#pragma unroll
                for (int mi = 0; mi < MF; ++mi)
#pragma unroll
                    for (int ni = 0; ni < NF; ++ni)
                        acc[mi][ni] = __builtin_amdgcn_mfma_f32_16x16x32_bf16(af[mi], bf[ni], acc[mi][ni], 0, 0, 0);
            }
            __syncthreads();
        }
    }
#pragma unroll
    for (int mi = 0; mi < MF; ++mi) {
#pragma unroll
        for (int ni = 0; ni < NF; ++ni) {
#pragma unroll
            for (int j = 0; j < 4; ++j) {
                int row = m0 + wr * (MF * 16) + mi * 16 + g * 4 + j;
                int col = n0 + wc * (NF * 16) + ni * 16 + fr;
                float v = acc[mi][ni][j];
                if (OUT_MODE != 3) v += bias[col];
                else if (sp == 0) v += bias[col];
                if (ACT == 1) v = 0.5f * v * (1.0f + erff(v * 0.70710678118654752f));
                if (RES) v += residual[(size_t)row * N + col];
                if (OUT_MODE == 0) {
                    Cf[(size_t)row * N + col] = v;
                } else if (OUT_MODE == 1) {
                    Cb[(size_t)row * N + col] = f2bf(v);
                } else if (OUT_MODE == 3) {
                    atomicAdd(&Cf[(size_t)row * N + col], v);
                } else {
                    int which = col >= 1536 ? 2 : (col >= 768 ? 1 : 0);
                    int rem = col - which * 768;
                    int hh = rem >> 6, d = rem & 63;
                    int b_ = row >> 10, t_ = row & 1023;
                    if (which == 2)
                        Vo[((size_t)(b_ * NH + hh) * HD + d) * Tc + t_] = f2bf(v);
                    else {
                        ushort* dst = which == 0 ? Qo : Ko;
                        dst[((size_t)(b_ * NH + hh) * Tc + t_) * HD + d] = f2bf(v);
                    }
                }
            }
        }
    }
}

// ============ FAST attention: P-store scheme, 2-wave blocks (R12 verbatim) ============
// Block = one 16-row q-tile (t = 0..63) of one head; 128 thr = 2 waves (kh key-halves).
// LPT: heavy tiles first. P = exp(s*0.125-8) bf16 in MFMA-A-fragment layout:
// lane l elem j <-> (q = l&15, k = k0 + (l>>4)*8 + j); 1KB / 32-key step.
// panel(bh,t) = Pbuf + (bh*1056 + (t+1)^2/4)*512 ushorts; nst(t) = (t+2)>>1 steps.

__global__ __launch_bounds__(128) void attn_P(
    const ushort* __restrict__ Qp, const ushort* __restrict__ Kp,
    ushort* __restrict__ Pbuf, float* __restrict__ denom, float* __restrict__ colsum) {
    int beta = blockIdx.x;
    int tq = 63 - beta / 48;
    int bh = beta % 48;
    int tid = threadIdx.x;
    int kh = tid >> 6, lane = tid & 63, qlane = lane & 15, g = lane >> 4;
    __shared__ ushort plds[2][16][48];
    __shared__ float cs[1056];
    __shared__ float dden[2][16];
    int nst = (tq + 2) >> 1;
    int smid = (nst + 1) >> 1;
    int slo = kh ? smid : 0, shi = kh ? nst : smid;  // per-wave <= 16 steps
    int kmaxc = (tq + 1) * 16;
    for (int i = tid; i < 1056; i += 128) cs[i] = 0.f;
    const ushort* Qb = Qp + (size_t)bh * Tc * HD;
    const ushort* Kb = Kp + (size_t)bh * Tc * HD;
    const ushort* qr = Qb + (size_t)(tq * 16 + qlane) * HD + g * 8;
    s16x8 qf0 = *(const s16x8*)qr;
    s16x8 qf1 = *(const s16x8*)(qr + 32);
    ushort* panel = Pbuf + ((size_t)bh * 1056 + (unsigned)(((tq + 1) * (tq + 1)) >> 2)) * 512;
    int q = tq * 16 + qlane;
    s16x8 preg[16];
    float dpart = 0.f;
#pragma unroll
    for (int ss = 0; ss < 16; ++ss) {
        int s = slo + ss;
        if (s < shi) {
            int kt0 = 2 * s, kt1 = 2 * s + 1;
            {
                const ushort* kr = Kb + (size_t)(kt0 * 16 + qlane) * HD + g * 8;
                s16x8 kf0 = *(const s16x8*)kr;
                s16x8 kf1 = *(const s16x8*)(kr + 32);
                f32x4 z = {0.f, 0.f, 0.f, 0.f};
                z = __builtin_amdgcn_mfma_f32_16x16x32_bf16(kf0, qf0, z, 0, 0, 0);
                z = __builtin_amdgcn_mfma_f32_16x16x32_bf16(kf1, qf1, z, 0, 0, 0);
#pragma unroll
                for (int j = 0; j < 4; ++j) {
                    int key = kt0 * 16 + g * 4 + j;
                    float p = (key <= q) ? __expf(z[j] * 0.125f - 8.f) : 0.f;
                    dpart += p;
                    plds[kh][qlane][g * 4 + j] = f2bf(p);
                }
            }
            if (kt1 <= tq) {
                const ushort* kr = Kb + (size_t)(kt1 * 16 + qlane) * HD + g * 8;
                s16x8 kf0 = *(const s16x8*)kr;
                s16x8 kf1 = *(const s16x8*)(kr + 32);
                f32x4 z = {0.f, 0.f, 0.f, 0.f};
                z = __builtin_amdgcn_mfma_f32_16x16x32_bf16(kf0, qf0, z, 0, 0, 0);
                z = __builtin_amdgcn_mfma_f32_16x16x32_bf16(kf1, qf1, z, 0, 0, 0);
#pragma unroll
                for (int j = 0; j < 4; ++j) {
                    int key = kt1 * 16 + g * 4 + j;
                    float p = (key <= q) ? __expf(z[j] * 0.125f - 8.f) : 0.f;
                    dpart += p;
                    plds[kh][qlane][16 + g * 4 + j] = f2bf(p);
                }
            } else {
#pragma unroll
                for (int j = 0; j < 4; ++j) plds[kh][qlane][16 + g * 4 + j] = 0;
            }
            s16x8 pa = *(const s16x8*)&plds[kh][qlane][g * 8];
            preg[ss] = pa;
            *(s16x8*)(panel + (size_t)s * 512 + lane * 8) = pa;
        }
    }
    dpart += __shfl_xor(dpart, 16);
    dpart += __shfl_xor(dpart, 32);
    if (lane < 16) dden[kh][lane] = dpart;
    __syncthreads();
    float dsum = dden[0][qlane] + dden[1][qlane];
    if (tid < 16) denom[(size_t)bh * Tc + tq * 16 + tid] = dden[0][tid] + dden[1][tid];
    float dinvq = rcp_f(dsum);
    // sweep B: colsum from registers (bit-identical to panel values)
#pragma unroll
    for (int ss = 0; ss < 16; ++ss) {
        int s = slo + ss;
        if (s < shi) {
            s16x8 v8 = preg[ss];
            int k0 = s * 32 + g * 8;
#pragma unroll
            for (int j = 0; j < 8; ++j) {
                float r = bf2f((ushort)v8[j]) * dinvq;
                r += __shfl_xor(r, 1);
                r += __shfl_xor(r, 2);
                r += __shfl_xor(r, 4);
                r += __shfl_xor(r, 8);
                if (qlane == 0) cs[k0 + j] += r;
            }
        }
    }
    __syncthreads();
    for (int i = tid; i < kmaxc; i += 128)
        atomicAdd(&colsum[(size_t)bh * Tc + i], cs[i]);
}

// attn_CD: one panel read; pt carried in registers between sweep C and sweep D.
__global__ __launch_bounds__(128) void attn_CD(
    const ushort* __restrict__ Pbuf, const ushort* __restrict__ Vt,
    const float* __restrict__ denom, const float* __restrict__ colsum,
    const float* __restrict__ refr_in,
    const float* __restrict__ threshold, const float* __restrict__ leak,
    const float* __restrict__ steepness, const float* __restrict__ refr_strength,
    const float* __restrict__ cross_w,
    ushort* __restrict__ ybuf, float* __restrict__ refr_out) {
    int beta = blockIdx.x;
    int tq = 63 - beta / 48;
    int bh = beta % 48;
    int b = bh / NH, h = bh - b * NH;
    int tid = threadIdx.x;
    int kh = tid >> 6, lane = tid & 63, qlane = lane & 15, g = lane >> 4;
    __shared__ float eff[1056];
    __shared__ float cs[1056];
    __shared__ float msum[2][16];
    __shared__ float minvL[16];
    __shared__ float ymrg[16][68];
    int nst = (tq + 2) >> 1;
    int smid = (nst + 1) >> 1;
    int slo = kh ? smid : 0, shi = kh ? nst : smid;  // per-wave <= 16 steps
    int kmaxc = (tq + 1) * 16;
    float thr = fabsf(threshold[h]) * 0.1f;
    float lk = 1.f / (1.f + __expf(-leak[h]));
    float lk1m = 1.f - lk;
    float stp = softplus_f(steepness[h]);
    float rfs = softplus_f(refr_strength[h]);
    float crw = 1.f / (1.f + __expf(-cross_w[h]));
    for (int i = tid; i < 1056; i += 128) {
        eff[i] = (i < kmaxc)
                     ? thr + rfs * (colsum[(size_t)bh * Tc + i] * (1.f / 1024.f))
                           + crw * refr_in[(size_t)b * Tc + i]
                     : 0.f;
        cs[i] = 0.f;
    }
    float dinvq = rcp_f(denom[(size_t)bh * Tc + tq * 16 + qlane]);
    __syncthreads();
    const ushort* panel =
        Pbuf + ((size_t)bh * 1056 + (unsigned)(((tq + 1) * (tq + 1)) >> 2)) * 512;
    // sweep C: single panel read; LIF modulation; pt kept in registers (static idx)
    s16x8 ptreg[16];
    float msp = 0.f;
#pragma unroll
    for (int ss = 0; ss < 16; ++ss) {
        int s = slo + ss;
        if (s < shi) {
            s16x8 v8 = *(const s16x8*)(panel + (size_t)s * 512 + lane * 8);
            int k0 = s * 32 + g * 8;
            s16x8 pw;
#pragma unroll
            for (int j = 0; j < 8; ++j) {
                float p = bf2f((ushort)v8[j]) * dinvq;
                float fire = rcp_f(1.f + __expf(-stp * (p - eff[k0 + j])));
                float pt = p * (lk + lk1m * fire);
                msp += pt;
                pw[j] = (short)f2bf(pt);
            }
            ptreg[ss] = pw;
        }
    }
    msp += __shfl_xor(msp, 16);
    msp += __shfl_xor(msp, 32);
    if (lane < 16) msum[kh][lane] = msp;
    __syncthreads();
    if (tid < 16) minvL[tid] = rcp_f(msum[0][tid] + msum[1][tid] + 1e-8f);
    __syncthreads();
    float minvq = minvL[qlane];
    const ushort* Vh = Vt + (size_t)bh * HD * Tc;
    f32x4 accY[4] = {};
    // sweep D: PV MFMA from registers + refractory colsum (cs[k] owned by one lane)
#pragma unroll
    for (int ss = 0; ss < 16; ++ss) {
        int s = slo + ss;
        if (s < shi) {
            s16x8 pa = ptreg[ss];
            int k0 = s * 32 + g * 8;
#pragma unroll
            for (int j = 0; j < 8; ++j) {
                float r = bf2f((ushort)pa[j]) * minvq;
                r += __shfl_xor(r, 1);
                r += __shfl_xor(r, 2);
                r += __shfl_xor(r, 4);
                r += __shfl_xor(r, 8);
                if (qlane == 0) cs[k0 + j] += r;
            }
#pragma unroll
            for (int dt = 0; dt < 4; ++dt) {
                const ushort* vp = Vh + (size_t)(dt * 16 + qlane) * Tc + s * 32 + g * 8;
                s16x8 vf = *(const s16x8*)vp;
                accY[dt] = __builtin_amdgcn_mfma_f32_16x16x32_bf16(pa, vf, accY[dt], 0, 0, 0);
            }
        }
    }
    if (kh == 1) {
#pragma unroll
        for (int dt = 0; dt < 4; ++dt)
#pragma unroll
            for (int j = 0; j < 4; ++j)
                ymrg[g * 4 + j][dt * 16 + qlane] = accY[dt][j];
    }
    __syncthreads();
    if (kh == 0) {
#pragma unroll
        for (int dt = 0; dt < 4; ++dt)
#pragma unroll
            for (int j = 0; j < 4; ++j) {
                float y = (accY[dt][j] + ymrg[g * 4 + j][dt * 16 + qlane]) * minvL[g * 4 + j];
                ybuf[(size_t)(b * Tc + tq * 16 + g * 4 + j) * NE + h * 64 + dt * 16 + qlane] =
                    f2bf(y);
            }
    }
    for (int i = tid; i < kmaxc; i += 128)
        atomicAdd(&refr_out[(size_t)b * Tc + i], cs[i] * (1.f / (NH * Tc)));
}

// ---------------- launcher ----------------
extern "C" void kernel_launch(void* const* d_in, const int* in_sizes, int n_in,
                              void* d_out, int out_size, void* d_ws, size_t ws_size,
                              hipStream_t stream) {
    const float* x        = (const float*)d_in[0];
    const float* refr     = (const float*)d_in[1];
    const float* ln1_w    = (const float*)d_in[2];
    const float* ln1_b    = (const float*)d_in[3];
    const float* c_attn_w = (const float*)d_in[4];
    const float* c_attn_b = (const float*)d_in[5];
    const float* c_proj_w = (const float*)d_in[6];
    const float* c_proj_b = (const float*)d_in[7];
    const float* threshold = (const float*)d_in[8];
    const float* leak      = (const float*)d_in[9];
    const float* steepness = (const float*)d_in[10];
    const float* refractory_strength = (const float*)d_in[11];
    const float* cross_layer_weight  = (const float*)d_in[12];
    const float* ln2_w    = (const float*)d_in[13];
    const float* ln2_b    = (const float*)d_in[14];
    const float* fc_w     = (const float*)d_in[15];
    const float* fc_b     = (const float*)d_in[16];
    const float* proj_w   = (const float*)d_in[17];
    const float* proj_b   = (const float*)d_in[18];

    // workspace layout (bytes)
    char* ws = (char*)d_ws;
    ushort* hbuf   = (ushort*)(ws + 0);         // bf16 [4096][768]
    ushort* qb     = (ushort*)(ws + 6291456);   // bf16 [b,h,t,d]
    ushort* kb     = (ushort*)(ws + 12582912);  // bf16 [b,h,t,d]
    ushort* vtg    = (ushort*)(ws + 18874368);  // bf16 V^T [b,h,d,t]
    ushort* ybuf   = (ushort*)(ws + 25165824);  // bf16 [4096][768]
    ushort* fc_act = (ushort*)(ws + 6291456);   // bf16 [4096][3072], overlaps q/k/v/y (post-attn)
    float*  denomb = (float*)(ws + 31457280);   // [48][1024]
    float*  colsum = (float*)(ws + 31653888);   // [48][1024]
    ushort* wt_attn  = (ushort*)(ws + 31850496);
    ushort* wt_cproj = (ushort*)(ws + 35389440);
    ushort* wt_fc    = (ushort*)(ws + 36569088);
    ushort* wt_proj  = (ushort*)(ws + 41287680);
    ushort* Pbuf     = (ushort*)(ws + 46006272); // bf16 packed causal P, 51,904,512 B

    float* xout = (float*)d_out;
    float* refr_out = xout + (size_t)BT * NE;

    // wconvert + zero colsum/refr_out + LN1: one launch
    // (6912 conv blocks + 52 zero blocks + 4096 LN rows)
    wconvert_all<<<11060, 256, 0, stream>>>(c_attn_w, wt_attn, c_proj_w, wt_cproj,
                                            fc_w, wt_fc, proj_w, wt_proj,
                                            colsum, refr_out, x, ln1_w, ln1_b, hbuf);

    // qkv: M=4096 N=2304 K=768, 64x128 tiles -> 1152 blocks
    mfma_gemm<64, 128, 2, 0, false><<<1152, 256, 0, stream>>>(
        hbuf, wt_attn, c_attn_b, nullptr, nullptr, nullptr, qb, kb, vtg,
        BT, 3 * NE, NE, 18, NE, 1);

    attn_P<<<48 * 64, 128, 0, stream>>>(qb, kb, Pbuf, denomb, colsum);
    attn_CD<<<48 * 64, 128, 0, stream>>>(
        Pbuf, vtg, denomb, colsum, refr, threshold, leak, steepness,
        refractory_strength, cross_layer_weight, ybuf, refr_out);

    // c_proj: M=4096 N=768 K=768, 64x64 dbuf tiles -> 768 blocks
    mfma_gemm<64, 64, 0, 0, true><<<768, 256, 0, stream>>>(
        ybuf, wt_cproj, c_proj_b, x, xout, nullptr, nullptr, nullptr, nullptr,
        BT, NE, NE, 12, NE, 1);

    ln_kernel<<<BT, 256, 0, stream>>>(xout, ln2_w, ln2_b, hbuf);

    // fc: M=4096 N=3072 K=768, 128x128 tiles -> 768 blocks
    mfma_gemm<128, 128, 1, 1, false><<<768, 256, 0, stream>>>(
        hbuf, wt_fc, fc_b, nullptr, nullptr, fc_act, nullptr, nullptr, nullptr,
        BT, 4 * NE, NE, 24, NE, 1);

    // proj: M=4096 N=768 K=3072, 64x64 dbuf tiles, split-K=2 -> 1536 blocks.
    // xout already holds the residual (written by c_proj); partials atomicAdd on top;
    // bias added by split 0 only.
    mfma_gemm<64, 64, 3, 0, false><<<1536, 256, 0, stream>>>(
        fc_act, wt_proj, proj_b, nullptr, xout, nullptr, nullptr, nullptr, nullptr,
        BT, NE, 4 * NE / 2, 12, 4 * NE, 2);
}

// Round 15
// 239.011 us; speedup vs baseline: 1.0853x; 1.0713x over previous
//
#include <hip/hip_runtime.h>
#include <hip/hip_bf16.h>
#include <math.h>

typedef unsigned short ushort;
typedef __attribute__((ext_vector_type(8))) unsigned short ushort8;
typedef __attribute__((ext_vector_type(8))) short s16x8;
typedef __attribute__((ext_vector_type(4))) float f32x4;

constexpr int NE = 768;      // N_EMBD
constexpr int NH = 12;       // heads
constexpr int HD = 64;       // head dim
constexpr int Bc = 4;
constexpr int Tc = 1024;
constexpr int BT = Bc * Tc;  // 4096 rows

__device__ __forceinline__ ushort f2bf(float f) {
    __hip_bfloat16 h = __float2bfloat16(f);
    return *reinterpret_cast<ushort*>(&h);
}
__device__ __forceinline__ float bf2f(ushort u) {
    return __uint_as_float(((unsigned)u) << 16);
}
__device__ __forceinline__ float softplus_f(float x) {
    return (x > 20.f) ? x : log1pf(__expf(x));
}
__device__ __forceinline__ float rcp_f(float x) {
#if __has_builtin(__builtin_amdgcn_rcpf)
    return __builtin_amdgcn_rcpf(x);
#else
    return 1.f / x;
#endif
}
__device__ __forceinline__ void gload16(const void* g, void* l) {
    __builtin_amdgcn_global_load_lds((const __attribute__((address_space(1))) void*)g,
                                     (__attribute__((address_space(3))) void*)l, 16, 0, 0);
}

// ---------------- LayerNorm: f32 in -> bf16 out (wave-shuffle reduce) ----------------
__device__ __forceinline__ void ln_row(const float* __restrict__ x,
                                       const float* __restrict__ w,
                                       const float* __restrict__ b,
                                       ushort* __restrict__ out, int row, int t) {
    const float* xr = x + (size_t)row * NE;
    float v0 = xr[t], v1 = xr[t + 256], v2 = xr[t + 512];
    float s = v0 + v1 + v2;
    float s2 = v0 * v0 + v1 * v1 + v2 * v2;
#pragma unroll
    for (int o = 32; o > 0; o >>= 1) {
        s += __shfl_xor(s, o);
        s2 += __shfl_xor(s2, o);
    }
    __shared__ float lws[4], lws2[4];
    int wv = t >> 6;
    if ((t & 63) == 0) { lws[wv] = s; lws2[wv] = s2; }
    __syncthreads();
    float sum = lws[0] + lws[1] + lws[2] + lws[3];
    float sq = lws2[0] + lws2[1] + lws2[2] + lws2[3];
    float mean = sum * (1.0f / NE);
    float var = sq * (1.0f / NE) - mean * mean;
    float rs = rsqrtf(var + 1e-5f);
    ushort* orow = out + (size_t)row * NE;
    orow[t]       = f2bf((v0 - mean) * rs * w[t]       + b[t]);
    orow[t + 256] = f2bf((v1 - mean) * rs * w[t + 256] + b[t + 256]);
    orow[t + 512] = f2bf((v2 - mean) * rs * w[t + 512] + b[t + 512]);
}

__global__ __launch_bounds__(256) void ln_kernel(const float* __restrict__ x,
                                                 const float* __restrict__ w,
                                                 const float* __restrict__ b,
                                                 ushort* __restrict__ out) {
    ln_row(x, w, b, out, blockIdx.x, threadIdx.x);
}

// ---------------- fused weight convert + zeroing + LN1: one launch ----------------
__device__ __forceinline__ void wconv_tile(const float* __restrict__ W,
                                           ushort* __restrict__ Wt,
                                           int K, int N, int bx, int by, int tid) {
    __shared__ float t[32][33];
    int n0 = bx * 32, k0 = by * 32;
    int c = tid & 31, r4 = tid >> 5;
#pragma unroll
    for (int i = 0; i < 4; ++i) {
        int r = r4 + i * 8;
        t[r][c] = W[(size_t)(k0 + r) * N + n0 + c];
    }
    __syncthreads();
#pragma unroll
    for (int i = 0; i < 4; ++i) {
        int r = r4 + i * 8;
        Wt[(size_t)(n0 + r) * K + k0 + c] = f2bf(t[c][r]);
    }
}

__global__ __launch_bounds__(256) void wconvert_all(
    const float* __restrict__ Wa, ushort* __restrict__ Ta,    // 768 x 2304
    const float* __restrict__ Wc, ushort* __restrict__ Tcp,   // 768 x 768
    const float* __restrict__ Wf, ushort* __restrict__ Tf,    // 768 x 3072
    const float* __restrict__ Wp, ushort* __restrict__ Tp,    // 3072 x 768
    float* __restrict__ colsum, float* __restrict__ refr_out,
    const float* __restrict__ x, const float* __restrict__ ln1_w,
    const float* __restrict__ ln1_b, ushort* __restrict__ hbuf) {
    int blk = blockIdx.x, tid = threadIdx.x;
    if (blk >= 6964) {
        // LN1: rows 0..4095
        ln_row(x, ln1_w, ln1_b, hbuf, blk - 6964, tid);
        return;
    }
    if (blk >= 6912) {
        int i = (blk - 6912) * 256 + tid;
        float4 z = make_float4(0.f, 0.f, 0.f, 0.f);
        if (i < 12288) ((float4*)colsum)[i] = z;
        else ((float4*)refr_out)[i - 12288] = z;
        return;
    }
    if (blk < 1728) {
        wconv_tile(Wa, Ta, 768, 2304, blk % 72, blk / 72, tid);
    } else if (blk < 2304) {
        int i = blk - 1728;
        wconv_tile(Wc, Tcp, 768, 768, i % 24, i / 24, tid);
    } else if (blk < 4608) {
        int i = blk - 2304;
        wconv_tile(Wf, Tf, 768, 3072, i % 96, i / 96, tid);
    } else {
        int i = blk - 4608;
        wconv_tile(Wp, Tp, 3072, 768, i % 24, i / 24, tid);
    }
}

// ---------------- MFMA GEMM ----------------
// 64x64 tiles use a 2-phase double-buffered pipeline (counted vmcnt, raw barriers);
// larger tiles keep the single-buffer loop.
// OUT_MODE: 0=f32 store, 1=bf16 store, 2=qkv scatter (V^T), 3=f32 atomicAdd (split-K).
// K = per-split K-length; KLD = leading dim of A/Bt; NSPLIT = K-splits (grid multiple).
template <int BM, int BN, int OUT_MODE, int ACT, bool RES>
__global__ __launch_bounds__(256) void mfma_gemm(
    const ushort* __restrict__ A, const ushort* __restrict__ Bt,
    const float* __restrict__ bias, const float* __restrict__ residual,
    float* __restrict__ Cf, ushort* __restrict__ Cb,
    ushort* __restrict__ Qo, ushort* __restrict__ Ko, ushort* __restrict__ Vo,
    int M, int N, int K, int NBX, int KLD, int NSPLIT) {
    constexpr int NF = (BM == 128) ? 4 : 2;
    constexpr int MF = (BM == 64 && BN == 64) ? 2 : 4;
    constexpr int WN = BN / (NF * 16);
    constexpr int APASS = BM / 32, BPASS = BN / 32;
    constexpr bool DBUF = (BM == 64 && BN == 64);
    constexpr int NBUF = DBUF ? 2 : 1;
    __shared__ __align__(16) ushort As[NBUF * BM * 64];
    __shared__ __align__(16) ushort Bs[NBUF * BN * 64];
    int tid = threadIdx.x;
    int lane = tid & 63;
    int nb = gridDim.x;
    int lin = blockIdx.x;
    int nl = (lin & 7) * (nb >> 3) + (lin >> 3);
    int nper = nb / NSPLIT;
    int sp = nl / nper;
    int rem2 = nl - sp * nper;
    int bx = rem2 % NBX, by = rem2 / NBX;
    int m0 = by * BM, n0 = bx * BN;
    int kbase = sp * K;
    int wave = tid >> 6;
    int wr = wave / WN, wc = wave % WN;
    f32x4 acc[MF][NF] = {};
    int srow = tid >> 3;
    int scol = (tid & 7) ^ (srow & 7);
    const ushort* ga = A + (size_t)(m0 + srow) * KLD + kbase + scol * 8;
    const ushort* gb = Bt + (size_t)(n0 + srow) * KLD + kbase + scol * 8;
    char* lA = (char*)As + tid * 16;
    char* lB = (char*)Bs + tid * 16;
    int fr = lane & 15, g = lane >> 4;
    unsigned swz = (unsigned)((fr & 7) << 4);
    const char* abase = (const char*)As + (wr * (MF * 16) + fr) * 128;
    const char* bbase = (const char*)Bs + (wc * (NF * 16) + fr) * 128;

    if constexpr (DBUF) {
        constexpr int ABYTES = BM * 64 * 2, BBYTES = BN * 64 * 2;
        int nk = K >> 6;
#pragma unroll
        for (int p = 0; p < APASS; ++p) gload16(ga + (size_t)(p * 32) * KLD, lA + p * 4096);
#pragma unroll
        for (int p = 0; p < BPASS; ++p) gload16(gb + (size_t)(p * 32) * KLD, lB + p * 4096);
        for (int k = 0; k < nk; ++k) {
            int cur = k & 1;
            if (k + 1 < nk) {
                int nxt = cur ^ 1;
                int k0 = (k + 1) << 6;
#pragma unroll
                for (int p = 0; p < APASS; ++p)
                    gload16(ga + (size_t)(p * 32) * KLD + k0, lA + nxt * ABYTES + p * 4096);
#pragma unroll
                for (int p = 0; p < BPASS; ++p)
                    gload16(gb + (size_t)(p * 32) * KLD + k0, lB + nxt * BBYTES + p * 4096);
                asm volatile("s_waitcnt vmcnt(4)" ::: "memory");
            } else {
                asm volatile("s_waitcnt vmcnt(0)" ::: "memory");
            }
            __builtin_amdgcn_s_barrier();
#pragma unroll
            for (int ks = 0; ks < 2; ++ks) {
                unsigned o = ((unsigned)(g * 16 + ks * 64)) ^ swz;
                s16x8 af[MF], bf[NF];
#pragma unroll
                for (int i = 0; i < MF; ++i)
                    af[i] = *(const s16x8*)(abase + cur * ABYTES + i * 2048 + o);
#pragma unroll
                for (int i = 0; i < NF; ++i)
                    bf[i] = *(const s16x8*)(bbase + cur * BBYTES + i * 2048 + o);
#pragma unroll
                for (int mi = 0; mi < MF; ++mi)
#pragma unroll
                    for (int ni = 0; ni < NF; ++ni)
                        acc[mi][ni] = __builtin_amdgcn_mfma_f32_16x16x32_bf16(af[mi], bf[ni], acc[mi][ni], 0, 0, 0);
            }
            asm volatile("s_waitcnt lgkmcnt(0)" ::: "memory");
            __builtin_amdgcn_s_barrier();
        }
    } else {
        for (int k0 = 0; k0 < K; k0 += 64) {
#pragma unroll
            for (int p = 0; p < APASS; ++p)
                gload16(ga + (size_t)(p * 32) * KLD + k0, lA + p * 4096);
#pragma unroll
            for (int p = 0; p < BPASS; ++p)
                gload16(gb + (size_t)(p * 32) * KLD + k0, lB + p * 4096);
            __syncthreads();
#pragma unroll
            for (int ks = 0; ks < 2; ++ks) {
                unsigned o = ((unsigned)(g * 16 + ks * 64)) ^ swz;
                s16x8 af[MF], bf[NF];
#pragma unroll
                for (int i = 0; i < MF; ++i) af[i] = *(const s16x8*)(abase + i * 2048 + o);
#pragma unroll
                for (int i = 0; i < NF; ++i) bf[i] = *(const s16x8*)(bbase + i * 2048 + o);
#pragma unroll
                for (int mi = 0; mi < MF; ++mi)
#pragma unroll
                    for (int ni = 0; ni < NF; ++ni)
                        acc[mi][ni] = __builtin_amdgcn_mfma_f32_16x16x32_bf16(af[mi], bf[ni], acc[mi][ni], 0, 0, 0);
            }
            __syncthreads();
        }
    }
#pragma unroll
    for (int mi = 0; mi < MF; ++mi) {
#pragma unroll
        for (int ni = 0; ni < NF; ++ni) {
#pragma unroll
            for (int j = 0; j < 4; ++j) {
                int row = m0 + wr * (MF * 16) + mi * 16 + g * 4 + j;
                int col = n0 + wc * (NF * 16) + ni * 16 + fr;
                float v = acc[mi][ni][j];
                if (OUT_MODE != 3) v += bias[col];
                else if (sp == 0) v += bias[col];
                if (ACT == 1) v = 0.5f * v * (1.0f + erff(v * 0.70710678118654752f));
                if (RES) v += residual[(size_t)row * N + col];
                if (OUT_MODE == 0) {
                    Cf[(size_t)row * N + col] = v;
                } else if (OUT_MODE == 1) {
                    Cb[(size_t)row * N + col] = f2bf(v);
                } else if (OUT_MODE == 3) {
                    atomicAdd(&Cf[(size_t)row * N + col], v);
                } else {
                    int which = col >= 1536 ? 2 : (col >= 768 ? 1 : 0);
                    int rem = col - which * 768;
                    int hh = rem >> 6, d = rem & 63;
                    int b_ = row >> 10, t_ = row & 1023;
                    if (which == 2)
                        Vo[((size_t)(b_ * NH + hh) * HD + d) * Tc + t_] = f2bf(v);
                    else {
                        ushort* dst = which == 0 ? Qo : Ko;
                        dst[((size_t)(b_ * NH + hh) * Tc + t_) * HD + d] = f2bf(v);
                    }
                }
            }
        }
    }
}

// ============ FAST attention: P-store scheme, 2-wave blocks (R12 verbatim) ============
// Block = one 16-row q-tile (t = 0..63) of one head; 128 thr = 2 waves (kh key-halves).
// LPT: heavy tiles first. P = exp(s*0.125-8) bf16 in MFMA-A-fragment layout:
// lane l elem j <-> (q = l&15, k = k0 + (l>>4)*8 + j); 1KB / 32-key step.
// panel(bh,t) = Pbuf + (bh*1056 + (t+1)^2/4)*512 ushorts; nst(t) = (t+2)>>1 steps.

__global__ __launch_bounds__(128) void attn_P(
    const ushort* __restrict__ Qp, const ushort* __restrict__ Kp,
    ushort* __restrict__ Pbuf, float* __restrict__ denom, float* __restrict__ colsum) {
    int beta = blockIdx.x;
    int tq = 63 - beta / 48;
    int bh = beta % 48;
    int tid = threadIdx.x;
    int kh = tid >> 6, lane = tid & 63, qlane = lane & 15, g = lane >> 4;
    __shared__ ushort plds[2][16][48];
    __shared__ float cs[1056];
    __shared__ float dden[2][16];
    int nst = (tq + 2) >> 1;
    int smid = (nst + 1) >> 1;
    int slo = kh ? smid : 0, shi = kh ? nst : smid;  // per-wave <= 16 steps
    int kmaxc = (tq + 1) * 16;
    for (int i = tid; i < 1056; i += 128) cs[i] = 0.f;
    const ushort* Qb = Qp + (size_t)bh * Tc * HD;
    const ushort* Kb = Kp + (size_t)bh * Tc * HD;
    const ushort* qr = Qb + (size_t)(tq * 16 + qlane) * HD + g * 8;
    s16x8 qf0 = *(const s16x8*)qr;
    s16x8 qf1 = *(const s16x8*)(qr + 32);
    ushort* panel = Pbuf + ((size_t)bh * 1056 + (unsigned)(((tq + 1) * (tq + 1)) >> 2)) * 512;
    int q = tq * 16 + qlane;
    s16x8 preg[16];
    float dpart = 0.f;
#pragma unroll
    for (int ss = 0; ss < 16; ++ss) {
        int s = slo + ss;
        if (s < shi) {
            int kt0 = 2 * s, kt1 = 2 * s + 1;
            {
                const ushort* kr = Kb + (size_t)(kt0 * 16 + qlane) * HD + g * 8;
                s16x8 kf0 = *(const s16x8*)kr;
                s16x8 kf1 = *(const s16x8*)(kr + 32);
                f32x4 z = {0.f, 0.f, 0.f, 0.f};
                z = __builtin_amdgcn_mfma_f32_16x16x32_bf16(kf0, qf0, z, 0, 0, 0);
                z = __builtin_amdgcn_mfma_f32_16x16x32_bf16(kf1, qf1, z, 0, 0, 0);
#pragma unroll
                for (int j = 0; j < 4; ++j) {
                    int key = kt0 * 16 + g * 4 + j;
                    float p = (key <= q) ? __expf(z[j] * 0.125f - 8.f) : 0.f;
                    dpart += p;
                    plds[kh][qlane][g * 4 + j] = f2bf(p);
                }
            }
            if (kt1 <= tq) {
                const ushort* kr = Kb + (size_t)(kt1 * 16 + qlane) * HD + g * 8;
                s16x8 kf0 = *(const s16x8*)kr;
                s16x8 kf1 = *(const s16x8*)(kr + 32);
                f32x4 z = {0.f, 0.f, 0.f, 0.f};
                z = __builtin_amdgcn_mfma_f32_16x16x32_bf16(kf0, qf0, z, 0, 0, 0);
                z = __builtin_amdgcn_mfma_f32_16x16x32_bf16(kf1, qf1, z, 0, 0, 0);
#pragma unroll
                for (int j = 0; j < 4; ++j) {
                    int key = kt1 * 16 + g * 4 + j;
                    float p = (key <= q) ? __expf(z[j] * 0.125f - 8.f) : 0.f;
                    dpart += p;
                    plds[kh][qlane][16 + g * 4 + j] = f2bf(p);
                }
            } else {
#pragma unroll
                for (int j = 0; j < 4; ++j) plds[kh][qlane][16 + g * 4 + j] = 0;
            }
            s16x8 pa = *(const s16x8*)&plds[kh][qlane][g * 8];
            preg[ss] = pa;
            *(s16x8*)(panel + (size_t)s * 512 + lane * 8) = pa;
        }
    }
    dpart += __shfl_xor(dpart, 16);
    dpart += __shfl_xor(dpart, 32);
    if (lane < 16) dden[kh][lane] = dpart;
    __syncthreads();
    float dsum = dden[0][qlane] + dden[1][qlane];
    if (tid < 16) denom[(size_t)bh * Tc + tq * 16 + tid] = dden[0][tid] + dden[1][tid];
    float dinvq = rcp_f(dsum);
    // sweep B: colsum from registers (bit-identical to panel values)
#pragma unroll
    for (int ss = 0; ss < 16; ++ss) {
        int s = slo + ss;
        if (s < shi) {
            s16x8 v8 = preg[ss];
            int k0 = s * 32 + g * 8;
#pragma unroll
            for (int j = 0; j < 8; ++j) {
                float r = bf2f((ushort)v8[j]) * dinvq;
                r += __shfl_xor(r, 1);
                r += __shfl_xor(r, 2);
                r += __shfl_xor(r, 4);
                r += __shfl_xor(r, 8);
                if (qlane == 0) cs[k0 + j] += r;
            }
        }
    }
    __syncthreads();
    for (int i = tid; i < kmaxc; i += 128)
        atomicAdd(&colsum[(size_t)bh * Tc + i], cs[i]);
}

// attn_CD: one panel read; pt carried in registers between sweep C and sweep D.
__global__ __launch_bounds__(128) void attn_CD(
    const ushort* __restrict__ Pbuf, const ushort* __restrict__ Vt,
    const float* __restrict__ denom, const float* __restrict__ colsum,
    const float* __restrict__ refr_in,
    const float* __restrict__ threshold, const float* __restrict__ leak,
    const float* __restrict__ steepness, const float* __restrict__ refr_strength,
    const float* __restrict__ cross_w,
    ushort* __restrict__ ybuf, float* __restrict__ refr_out) {
    int beta = blockIdx.x;
    int tq = 63 - beta / 48;
    int bh = beta % 48;
    int b = bh / NH, h = bh - b * NH;
    int tid = threadIdx.x;
    int kh = tid >> 6, lane = tid & 63, qlane = lane & 15, g = lane >> 4;
    __shared__ float eff[1056];
    __shared__ float cs[1056];
    __shared__ float msum[2][16];
    __shared__ float minvL[16];
    __shared__ float ymrg[16][68];
    int nst = (tq + 2) >> 1;
    int smid = (nst + 1) >> 1;
    int slo = kh ? smid : 0, shi = kh ? nst : smid;  // per-wave <= 16 steps
    int kmaxc = (tq + 1) * 16;
    float thr = fabsf(threshold[h]) * 0.1f;
    float lk = 1.f / (1.f + __expf(-leak[h]));
    float lk1m = 1.f - lk;
    float stp = softplus_f(steepness[h]);
    float rfs = softplus_f(refr_strength[h]);
    float crw = 1.f / (1.f + __expf(-cross_w[h]));
    for (int i = tid; i < 1056; i += 128) {
        eff[i] = (i < kmaxc)
                     ? thr + rfs * (colsum[(size_t)bh * Tc + i] * (1.f / 1024.f))
                           + crw * refr_in[(size_t)b * Tc + i]
                     : 0.f;
        cs[i] = 0.f;
    }
    float dinvq = rcp_f(denom[(size_t)bh * Tc + tq * 16 + qlane]);
    __syncthreads();
    const ushort* panel =
        Pbuf + ((size_t)bh * 1056 + (unsigned)(((tq + 1) * (tq + 1)) >> 2)) * 512;
    // sweep C: single panel read; LIF modulation; pt kept in registers (static idx)
    s16x8 ptreg[16];
    float msp = 0.f;
#pragma unroll
    for (int ss = 0; ss < 16; ++ss) {
        int s = slo + ss;
        if (s < shi) {
            s16x8 v8 = *(const s16x8*)(panel + (size_t)s * 512 + lane * 8);
            int k0 = s * 32 + g * 8;
            s16x8 pw;
#pragma unroll
            for (int j = 0; j < 8; ++j) {
                float p = bf2f((ushort)v8[j]) * dinvq;
                float fire = rcp_f(1.f + __expf(-stp * (p - eff[k0 + j])));
                float pt = p * (lk + lk1m * fire);
                msp += pt;
                pw[j] = (short)f2bf(pt);
            }
            ptreg[ss] = pw;
        }
    }
    msp += __shfl_xor(msp, 16);
    msp += __shfl_xor(msp, 32);
    if (lane < 16) msum[kh][lane] = msp;
    __syncthreads();
    if (tid < 16) minvL[tid] = rcp_f(msum[0][tid] + msum[1][tid] + 1e-8f);
    __syncthreads();
    float minvq = minvL[qlane];
    const ushort* Vh = Vt + (size_t)bh * HD * Tc;
    f32x4 accY[4] = {};
    // sweep D: PV MFMA from registers + refractory colsum (cs[k] owned by one lane)
#pragma unroll
    for (int ss = 0; ss < 16; ++ss) {
        int s = slo + ss;
        if (s < shi) {
            s16x8 pa = ptreg[ss];
            int k0 = s * 32 + g * 8;
#pragma unroll
            for (int j = 0; j < 8; ++j) {
                float r = bf2f((ushort)pa[j]) * minvq;
                r += __shfl_xor(r, 1);
                r += __shfl_xor(r, 2);
                r += __shfl_xor(r, 4);
                r += __shfl_xor(r, 8);
                if (qlane == 0) cs[k0 + j] += r;
            }
#pragma unroll
            for (int dt = 0; dt < 4; ++dt) {
                const ushort* vp = Vh + (size_t)(dt * 16 + qlane) * Tc + s * 32 + g * 8;
                s16x8 vf = *(const s16x8*)vp;
                accY[dt] = __builtin_amdgcn_mfma_f32_16x16x32_bf16(pa, vf, accY[dt], 0, 0, 0);
            }
        }
    }
    if (kh == 1) {
#pragma unroll
        for (int dt = 0; dt < 4; ++dt)
#pragma unroll
            for (int j = 0; j < 4; ++j)
                ymrg[g * 4 + j][dt * 16 + qlane] = accY[dt][j];
    }
    __syncthreads();
    if (kh == 0) {
#pragma unroll
        for (int dt = 0; dt < 4; ++dt)
#pragma unroll
            for (int j = 0; j < 4; ++j) {
                float y = (accY[dt][j] + ymrg[g * 4 + j][dt * 16 + qlane]) * minvL[g * 4 + j];
                ybuf[(size_t)(b * Tc + tq * 16 + g * 4 + j) * NE + h * 64 + dt * 16 + qlane] =
                    f2bf(y);
            }
    }
    for (int i = tid; i < kmaxc; i += 128)
        atomicAdd(&refr_out[(size_t)b * Tc + i], cs[i] * (1.f / (NH * Tc)));
}

// ---------------- launcher ----------------
extern "C" void kernel_launch(void* const* d_in, const int* in_sizes, int n_in,
                              void* d_out, int out_size, void* d_ws, size_t ws_size,
                              hipStream_t stream) {
    const float* x        = (const float*)d_in[0];
    const float* refr     = (const float*)d_in[1];
    const float* ln1_w    = (const float*)d_in[2];
    const float* ln1_b    = (const float*)d_in[3];
    const float* c_attn_w = (const float*)d_in[4];
    const float* c_attn_b = (const float*)d_in[5];
    const float* c_proj_w = (const float*)d_in[6];
    const float* c_proj_b = (const float*)d_in[7];
    const float* threshold = (const float*)d_in[8];
    const float* leak      = (const float*)d_in[9];
    const float* steepness = (const float*)d_in[10];
    const float* refractory_strength = (const float*)d_in[11];
    const float* cross_layer_weight  = (const float*)d_in[12];
    const float* ln2_w    = (const float*)d_in[13];
    const float* ln2_b    = (const float*)d_in[14];
    const float* fc_w     = (const float*)d_in[15];
    const float* fc_b     = (const float*)d_in[16];
    const float* proj_w   = (const float*)d_in[17];
    const float* proj_b   = (const float*)d_in[18];

    // workspace layout (bytes)
    char* ws = (char*)d_ws;
    ushort* hbuf   = (ushort*)(ws + 0);         // bf16 [4096][768]
    ushort* qb     = (ushort*)(ws + 6291456);   // bf16 [b,h,t,d]
    ushort* kb     = (ushort*)(ws + 12582912);  // bf16 [b,h,t,d]
    ushort* vtg    = (ushort*)(ws + 18874368);  // bf16 V^T [b,h,d,t]
    ushort* ybuf   = (ushort*)(ws + 25165824);  // bf16 [4096][768]
    ushort* fc_act = (ushort*)(ws + 6291456);   // bf16 [4096][3072], overlaps q/k/v/y (post-attn)
    float*  denomb = (float*)(ws + 31457280);   // [48][1024]
    float*  colsum = (float*)(ws + 31653888);   // [48][1024]
    ushort* wt_attn  = (ushort*)(ws + 31850496);
    ushort* wt_cproj = (ushort*)(ws + 35389440);
    ushort* wt_fc    = (ushort*)(ws + 36569088);
    ushort* wt_proj  = (ushort*)(ws + 41287680);
    ushort* Pbuf     = (ushort*)(ws + 46006272); // bf16 packed causal P, 51,904,512 B

    float* xout = (float*)d_out;
    float* refr_out = xout + (size_t)BT * NE;

    // wconvert + zero colsum/refr_out + LN1: one launch
    // (6912 conv blocks + 52 zero blocks + 4096 LN rows)
    wconvert_all<<<11060, 256, 0, stream>>>(c_attn_w, wt_attn, c_proj_w, wt_cproj,
                                            fc_w, wt_fc, proj_w, wt_proj,
                                            colsum, refr_out, x, ln1_w, ln1_b, hbuf);

    // qkv: M=4096 N=2304 K=768, 64x128 tiles -> 1152 blocks
    mfma_gemm<64, 128, 2, 0, false><<<1152, 256, 0, stream>>>(
        hbuf, wt_attn, c_attn_b, nullptr, nullptr, nullptr, qb, kb, vtg,
        BT, 3 * NE, NE, 18, NE, 1);

    attn_P<<<48 * 64, 128, 0, stream>>>(qb, kb, Pbuf, denomb, colsum);
    attn_CD<<<48 * 64, 128, 0, stream>>>(
        Pbuf, vtg, denomb, colsum, refr, threshold, leak, steepness,
        refractory_strength, cross_layer_weight, ybuf, refr_out);

    // c_proj: M=4096 N=768 K=768, 64x64 dbuf tiles -> 768 blocks
    mfma_gemm<64, 64, 0, 0, true><<<768, 256, 0, stream>>>(
        ybuf, wt_cproj, c_proj_b, x, xout, nullptr, nullptr, nullptr, nullptr,
        BT, NE, NE, 12, NE, 1);

    ln_kernel<<<BT, 256, 0, stream>>>(xout, ln2_w, ln2_b, hbuf);

    // fc: M=4096 N=3072 K=768, 128x128 tiles -> 768 blocks
    mfma_gemm<128, 128, 1, 1, false><<<768, 256, 0, stream>>>(
        hbuf, wt_fc, fc_b, nullptr, nullptr, fc_act, nullptr, nullptr, nullptr,
        BT, 4 * NE, NE, 24, NE, 1);

    // proj: M=4096 N=768 K=3072, 64x64 dbuf tiles -> 768 blocks (R12 config)
    mfma_gemm<64, 64, 0, 0, true><<<768, 256, 0, stream>>>(
        fc_act, wt_proj, proj_b, xout, xout, nullptr, nullptr, nullptr, nullptr,
        BT, NE, 4 * NE, 12, 4 * NE, 1);
}